// Round 1
// baseline (246.343 us; speedup 1.0000x reference)
//
#include <hip/hip_runtime.h>

#define B_   32
#define T_   8192
#define F_   16
#define HID_ 128
#define OUT_ 24
#define K1_  10
#define ND   19   // combined kernel width = 10 + 10 - 1

// Workspace layout (floats): [0, 7296) = W2[(j*19+d)*16+i], [7296, 7320) = Bc[j]

// ---------------- W2 precompute: W2[j,d,i] = sum_{k} sum_c wf[j,k*128+c] * w1[c,i,d-k]
__global__ void w2_kernel(const float* __restrict__ w1, const float* __restrict__ wf,
                          float* __restrict__ w2) {
    int blk = blockIdx.x;          // 456 = 24*19 blocks
    int j = blk / ND, d = blk % ND;
    int c = threadIdx.x;           // 128 threads
    __shared__ float red[16][128];
    float p[16];
#pragma unroll
    for (int i = 0; i < 16; ++i) p[i] = 0.f;
    int klo = d - 9 > 0 ? d - 9 : 0;
    int khi = d < 9 ? d : 9;
    for (int k = klo; k <= khi; ++k) {
        float wfv = wf[j * 1280 + k * 128 + c];
        int k2 = d - k;
#pragma unroll
        for (int i = 0; i < 16; ++i)
            p[i] = fmaf(wfv, w1[(c * 16 + i) * 10 + k2], p[i]);
    }
#pragma unroll
    for (int i = 0; i < 16; ++i) red[i][c] = p[i];
    __syncthreads();
    for (int off = 64; off > 0; off >>= 1) {
        if (c < off) {
#pragma unroll
            for (int i = 0; i < 16; ++i) red[i][c] += red[i][c + off];
        }
        __syncthreads();
    }
    if (c < 16) w2[(j * ND + d) * 16 + c] = red[c][0];
}

// ---------------- Bc[j] = bf[j] + sum_c b1[c] * sum_k wf[j,k*128+c]
__global__ void bc_kernel(const float* __restrict__ b1, const float* __restrict__ wf,
                          const float* __restrict__ bf, float* __restrict__ bc) {
    int j = blockIdx.x;            // 24 blocks
    int c = threadIdx.x;           // 128 threads
    float s = 0.f;
#pragma unroll
    for (int k = 0; k < K1_; ++k) s += wf[j * 1280 + k * 128 + c];
    s *= b1[c];
    __shared__ float red[128];
    red[c] = s;
    __syncthreads();
    for (int off = 64; off > 0; off >>= 1) {
        if (c < off) red[c] += red[c + off];
        __syncthreads();
    }
    if (c == 0) bc[j] = bf[j] + red[0];
}

// ---------------- head: exact two-stage path for t in [0,9) (replicate-clamp active)
__global__ void head_kernel(const float* __restrict__ x, const float* __restrict__ w1,
                            const float* __restrict__ b1, const float* __restrict__ wf,
                            const float* __restrict__ bf, float* __restrict__ out) {
    int b = blockIdx.x;            // 32 blocks
    int tid = threadIdx.x;         // 256 threads
    __shared__ float hh[9][128];
    const float* xb = x + (long)b * T_ * F_;
    for (int idx = tid; idx < 9 * 128; idx += 256) {
        int u = idx >> 7, c = idx & 127;
        float h = b1[c];
        for (int k = 9 - u; k <= 9; ++k) {
            int tau = u + k - 9;   // >= 0 by loop bound
#pragma unroll
            for (int i = 0; i < 16; ++i)
                h = fmaf(xb[tau * 16 + i], w1[(c * 16 + i) * 10 + k], h);
        }
        hh[u][c] = h;
    }
    __syncthreads();
    if (tid < 9 * OUT_) {
        int t = tid / OUT_, j = tid % OUT_;
        float y = bf[j];
        for (int k = 0; k < K1_; ++k) {
            int u = t + k - 9;
            if (u < 0) u = 0;
            const float* wrow = wf + j * 1280 + k * 128;
            for (int c = 0; c < 128; ++c) y = fmaf(wrow[c], hh[u][c], y);
        }
        out[((long)b * T_ + t) * OUT_ + j] = y;
    }
}

// ---------------- main: fused width-19 conv via W2, t in [9, T)
__device__ __forceinline__ float dot4f(float4 w, float4 v, float acc) {
    acc = fmaf(w.x, v.x, acc);
    acc = fmaf(w.y, v.y, acc);
    acc = fmaf(w.z, v.z, acc);
    acc = fmaf(w.w, v.w, acc);
    return acc;
}

__global__ __launch_bounds__(128) void main_kernel(const float* __restrict__ x,
                                                   const float* __restrict__ w2g,
                                                   float* __restrict__ out) {
    __shared__ float W2s[OUT_ * ND * 16];   // 29184 B
    __shared__ float Bcs[OUT_];
    int tid = threadIdx.x;                  // 128 threads, TPT=2 -> tile of 256 t
    int b = blockIdx.y;
    int t0 = blockIdx.x * 256;

    for (int idx = tid; idx < OUT_ * ND * 4; idx += 128)
        ((float4*)W2s)[idx] = ((const float4*)w2g)[idx];
    if (tid < OUT_) Bcs[tid] = w2g[OUT_ * ND * 16 + tid];
    __syncthreads();

    float acc0[OUT_], acc1[OUT_];
#pragma unroll
    for (int j = 0; j < OUT_; ++j) { acc0[j] = Bcs[j]; acc1[j] = Bcs[j]; }

    int ta = t0 + tid;        // this thread's first timestep
    int tb = ta + 128;        // second timestep (always >= 128)
    const float* xb = x + (long)b * T_ * F_;

#pragma unroll 1
    for (int d = 0; d < ND; ++d) {
        int r0 = ta + d - 18;
        int r1 = tb + d - 18;
        float4 v0[4], v1[4];
        if (r0 >= 0) {
            const float4* p = (const float4*)(xb + (long)r0 * 16);
            v0[0] = p[0]; v0[1] = p[1]; v0[2] = p[2]; v0[3] = p[3];
        } else {
            v0[0] = v0[1] = v0[2] = v0[3] = make_float4(0.f, 0.f, 0.f, 0.f);
        }
        if (r1 >= 0) {
            const float4* p = (const float4*)(xb + (long)r1 * 16);
            v1[0] = p[0]; v1[1] = p[1]; v1[2] = p[2]; v1[3] = p[3];
        } else {
            v1[0] = v1[1] = v1[2] = v1[3] = make_float4(0.f, 0.f, 0.f, 0.f);
        }
#pragma unroll
        for (int j = 0; j < OUT_; ++j) {
            const float4* w = (const float4*)&W2s[(j * ND + d) * 16];
            float4 w0 = w[0], w1v = w[1], w2v = w[2], w3v = w[3];
            acc0[j] = dot4f(w0, v0[0], acc0[j]);
            acc0[j] = dot4f(w1v, v0[1], acc0[j]);
            acc0[j] = dot4f(w2v, v0[2], acc0[j]);
            acc0[j] = dot4f(w3v, v0[3], acc0[j]);
            acc1[j] = dot4f(w0, v1[0], acc1[j]);
            acc1[j] = dot4f(w1v, v1[1], acc1[j]);
            acc1[j] = dot4f(w2v, v1[2], acc1[j]);
            acc1[j] = dot4f(w3v, v1[3], acc1[j]);
        }
    }

    if (ta >= 9) {   // t < 9 handled exactly by head_kernel
        float4* o = (float4*)(out + ((long)b * T_ + ta) * OUT_);
        o[0] = make_float4(acc0[0], acc0[1], acc0[2], acc0[3]);
        o[1] = make_float4(acc0[4], acc0[5], acc0[6], acc0[7]);
        o[2] = make_float4(acc0[8], acc0[9], acc0[10], acc0[11]);
        o[3] = make_float4(acc0[12], acc0[13], acc0[14], acc0[15]);
        o[4] = make_float4(acc0[16], acc0[17], acc0[18], acc0[19]);
        o[5] = make_float4(acc0[20], acc0[21], acc0[22], acc0[23]);
    }
    {
        float4* o = (float4*)(out + ((long)b * T_ + tb) * OUT_);
        o[0] = make_float4(acc1[0], acc1[1], acc1[2], acc1[3]);
        o[1] = make_float4(acc1[4], acc1[5], acc1[6], acc1[7]);
        o[2] = make_float4(acc1[8], acc1[9], acc1[10], acc1[11]);
        o[3] = make_float4(acc1[12], acc1[13], acc1[14], acc1[15]);
        o[4] = make_float4(acc1[16], acc1[17], acc1[18], acc1[19]);
        o[5] = make_float4(acc1[20], acc1[21], acc1[22], acc1[23]);
    }
}

extern "C" void kernel_launch(void* const* d_in, const int* in_sizes, int n_in,
                              void* d_out, int out_size, void* d_ws, size_t ws_size,
                              hipStream_t stream) {
    const float* x  = (const float*)d_in[0];
    const float* w1 = (const float*)d_in[1];
    const float* b1 = (const float*)d_in[2];
    const float* wf = (const float*)d_in[3];
    const float* bf = (const float*)d_in[4];
    float* out = (float*)d_out;
    float* w2  = (float*)d_ws;    // 7296 + 24 floats

    hipLaunchKernelGGL(w2_kernel, dim3(OUT_ * ND), dim3(128), 0, stream, w1, wf, w2);
    hipLaunchKernelGGL(bc_kernel, dim3(OUT_), dim3(128), 0, stream, b1, wf, bf, w2 + OUT_ * ND * 16);
    hipLaunchKernelGGL(main_kernel, dim3(T_ / 256, B_), dim3(128), 0, stream, x, w2, out);
    hipLaunchKernelGGL(head_kernel, dim3(B_), dim3(256), 0, stream, x, w1, b1, wf, bf, out);
}